// Round 1
// 517.247 us; speedup vs baseline: 1.0176x; 1.0176x over previous
//
#include <hip/hip_runtime.h>

// Problem constants: B=4, S=4096, H=1024, R=16
#define BQ 4
#define SQ 4096
#define HQ 1024
#define RQ 16
#define NROWS (BQ * SQ)   // 16384
#define PITCH 36          // PU cols: 0-15 scaled P, 16-31 U, 32 V, 33-35 pad
#define PITCH4 9

typedef float vfloat4 __attribute__((ext_vector_type(4)));

// ---------------------------------------------------------------------------
// besum[h] = sum_r be[r][h]
// ---------------------------------------------------------------------------
__global__ void besum_kernel(const float* __restrict__ be, float* __restrict__ besum) {
    int h = blockIdx.x * 256 + threadIdx.x;
    float s = 0.f;
#pragma unroll
    for (int r = 0; r < RQ; ++r) s += be[r * HQ + h];
    besum[h] = s;
}

// ---------------------------------------------------------------------------
// proj: [16384 x 1024] x [1024 x 33] -> PU[row][36], full K in-register.
// 64 rows/block, grid 256 (1 block/CU), 512 threads = 8 waves.
// Wave w owns cols 4w..4w+3 (wave-uniform -> scalar weight loads); lane = row.
// LDS: 64x64 f32 tile, double-buffered (32 KB), XOR-swizzled (chunk ^= row&7)
// so ds_read_b128 at 256B row pitch is conflict-free. Next tile's global
// loads issued before the barrier so HBM latency hides under the j-loop.
// Epilogue folds (dot + bc)*strength -> no reduce pass needed.
// ---------------------------------------------------------------------------
__global__ void __launch_bounds__(512, 2)
proj_kernel(const float* __restrict__ hs, const float* __restrict__ wc,
            const float* __restrict__ we, const float* __restrict__ besum,
            const float* __restrict__ bc, const float* __restrict__ strength,
            float* __restrict__ PU) {
    __shared__ float lds[2][64 * 64];
    const int tid = threadIdx.x;
    const int lane = tid & 63;
    const int wave = __builtin_amdgcn_readfirstlane(tid >> 6);
    const int R0 = blockIdx.x * 64;
    const int c0 = wave * 4;
    const float* wbase = (c0 < 16) ? (wc + c0 * HQ) : (we + (c0 - 16) * HQ);

    // Stage geometry: tile = 64 rows x 16 float4-chunks = 1024 chunks,
    // 512 threads -> chunks tid and tid+512. Global load fully coalesced;
    // LDS write slot = chunk ^ (row & 7)  (both-sides swizzle).
    const int r0s = tid >> 4;
    const int m0s = tid & 15;
    const int r1s = r0s + 32;
    const int l0 = r0s * 64 + ((m0s ^ (r0s & 7)) << 2);
    const int l1 = r1s * 64 + ((m0s ^ (r1s & 7)) << 2);
    const size_t g0 = (size_t)(R0 + r0s) * HQ + (m0s << 2);
    const size_t g1 = (size_t)(R0 + r1s) * HQ + (m0s << 2);
    const int e = lane & 7;

    float acc0 = 0.f, acc1 = 0.f, acc2 = 0.f, acc3 = 0.f, vacc = 0.f;

    float4 sa = *(const float4*)(hs + g0);
    float4 sb = *(const float4*)(hs + g1);

    for (int kc = 0; kc < 16; ++kc) {
        const int k0 = kc * 64;
        float* buf = lds[kc & 1];
        *(float4*)&buf[l0] = sa;
        *(float4*)&buf[l1] = sb;
        if (kc < 15) {  // early-issue next tile (latency hides under compute)
            sa = *(const float4*)(hs + g0 + k0 + 64);
            sb = *(const float4*)(hs + g1 + k0 + 64);
        }
        __syncthreads();  // single barrier/iter: double buffer covers WAR
#pragma unroll
        for (int j = 0; j < 16; ++j) {
            float4 w0 = *(const float4*)(wbase + 0 * HQ + k0 + 4 * j);
            float4 w1 = *(const float4*)(wbase + 1 * HQ + k0 + 4 * j);
            float4 w2 = *(const float4*)(wbase + 2 * HQ + k0 + 4 * j);
            float4 w3 = *(const float4*)(wbase + 3 * HQ + k0 + 4 * j);
            // swizzled read: LDS slot (j^e) of row 'lane' holds global chunk j
            const float4 h = *(const float4*)&buf[lane * 64 + ((j ^ e) << 2)];
            acc0 = fmaf(h.x, w0.x, fmaf(h.y, w0.y, fmaf(h.z, w0.z, fmaf(h.w, w0.w, acc0))));
            acc1 = fmaf(h.x, w1.x, fmaf(h.y, w1.y, fmaf(h.z, w1.z, fmaf(h.w, w1.w, acc1))));
            acc2 = fmaf(h.x, w2.x, fmaf(h.y, w2.y, fmaf(h.z, w2.z, fmaf(h.w, w2.w, acc2))));
            acc3 = fmaf(h.x, w3.x, fmaf(h.y, w3.y, fmaf(h.z, w3.z, fmaf(h.w, w3.w, acc3))));
            if (wave == 0) {
                float4 b4 = *(const float4*)(besum + k0 + 4 * j);
                vacc = fmaf(h.x, b4.x, fmaf(h.y, b4.y, fmaf(h.z, b4.z, fmaf(h.w, b4.w, vacc))));
            }
        }
        __syncthreads();  // all reads of buf done before it's overwritten
    }

    const int row = R0 + lane;
    const size_t base = (size_t)row * PITCH;
    float4 o;
    if (wave < 4) {
        const float4 st = *(const float4*)(strength + c0);
        const float4 b4 = *(const float4*)(bc + c0);
        o.x = (acc0 + b4.x) * st.x;
        o.y = (acc1 + b4.y) * st.y;
        o.z = (acc2 + b4.z) * st.z;
        o.w = (acc3 + b4.w) * st.w;
    } else {
        o = make_float4(acc0, acc1, acc2, acc3);
    }
    *(float4*)(PU + base + c0) = o;
    if (wave == 0) PU[base + 32] = vacc;
}

// ---------------------------------------------------------------------------
// bias[b,s,t] = sum_r P[b,s,r]*U[b,t,r] + V[b,t]
// 64x64 tile / block, 4sx4t per thread; k looped in quads to keep VGPRs low.
// ---------------------------------------------------------------------------
__global__ void __launch_bounds__(256)
bias_kernel(const float* __restrict__ PU, float* __restrict__ out) {
    const int b = blockIdx.z;
    const int ts = threadIdx.x & 15;
    const int ss = threadIdx.x >> 4;
    const int t0 = blockIdx.x * 64 + ts * 4;
    const int s0 = blockIdx.y * 64 + ss * 4;
    const float4* PU4 = (const float4*)PU;
    const size_t rbase = (size_t)b * SQ;

    float acc[4][4] = {{0.f}};
#pragma unroll
    for (int kq = 0; kq < 4; ++kq) {
        float4 p[4], u[4];
#pragma unroll
        for (int i = 0; i < 4; ++i) p[i] = PU4[(rbase + s0 + i) * PITCH4 + kq];
#pragma unroll
        for (int j = 0; j < 4; ++j) u[j] = PU4[(rbase + t0 + j) * PITCH4 + 4 + kq];
#pragma unroll
        for (int i = 0; i < 4; ++i)
#pragma unroll
            for (int j = 0; j < 4; ++j)
                acc[i][j] = fmaf(p[i].x, u[j].x, fmaf(p[i].y, u[j].y,
                            fmaf(p[i].z, u[j].z, fmaf(p[i].w, u[j].w, acc[i][j]))));
    }
    float v[4];
#pragma unroll
    for (int j = 0; j < 4; ++j) v[j] = PU[(rbase + t0 + j) * PITCH + 32];
#pragma unroll
    for (int i = 0; i < 4; ++i) {
        vfloat4 o;
        o.x = acc[i][0] + v[0];
        o.y = acc[i][1] + v[1];
        o.z = acc[i][2] + v[2];
        o.w = acc[i][3] + v[3];
        __builtin_nontemporal_store(o, (vfloat4*)(out + (rbase + s0 + i) * SQ + t0));
    }
}

// ---------------------------------------------------------------------------
extern "C" void kernel_launch(void* const* d_in, const int* in_sizes, int n_in,
                              void* d_out, int out_size, void* d_ws, size_t ws_size,
                              hipStream_t stream) {
    const float* hs       = (const float*)d_in[0];  // [B,S,H]
    const float* wc       = (const float*)d_in[1];  // [R,H]
    const float* bc       = (const float*)d_in[2];  // [R]
    const float* we       = (const float*)d_in[3];  // [R,H]
    const float* be       = (const float*)d_in[4];  // [R,H]
    const float* strength = (const float*)d_in[5];  // [R]
    float* out = (float*)d_out;                     // [B,S,S]

    float* ws    = (float*)d_ws;
    float* besum = ws;              // 1024 floats
    float* PU    = besum + HQ;      // 16384*36 floats (~2.4 MB)

    besum_kernel<<<dim3(HQ / 256), dim3(256), 0, stream>>>(be, besum);
    proj_kernel<<<dim3(NROWS / 64), dim3(512), 0, stream>>>(hs, wc, we, besum, bc, strength, PU);
    bias_kernel<<<dim3(SQ / 64, SQ / 64, BQ), dim3(256), 0, stream>>>(PU, out);
}

// Round 2
// 451.276 us; speedup vs baseline: 1.1663x; 1.1462x over previous
//
#include <hip/hip_runtime.h>

// Problem constants: B=4, S=4096, H=1024, R=16
#define BQ 4
#define SQ 4096
#define HQ 1024
#define RQ 16
#define NROWS (BQ * SQ)   // 16384
#define PITCH 36          // PU cols: 0-15 scaled P, 16-31 U, 32 V, 33-35 pad
#define PITCH4 9

typedef float vfloat4 __attribute__((ext_vector_type(4)));

// ---------------------------------------------------------------------------
// besum[h] = sum_r be[r][h]
// ---------------------------------------------------------------------------
__global__ void besum_kernel(const float* __restrict__ be, float* __restrict__ besum) {
    int h = blockIdx.x * 256 + threadIdx.x;
    float s = 0.f;
#pragma unroll
    for (int r = 0; r < RQ; ++r) s += be[r * HQ + h];
    besum[h] = s;
}

// ---------------------------------------------------------------------------
// proj: [16384 x 1024] x [1024 x 33] -> PU[row][36], full K in-register.
// 64 rows/block, grid 256 (1 block/CU), 1024 threads = 16 waves = 4/SIMD.
// Wave-group wg = wave>>3 splits each 64-col K-chunk: wg0 does j 0-7,
// wg1 does j 8-15; partials combined via LDS at the end.
// Wave w8 = wave&7 owns cols 4*w8..4*w8+3 (wave-uniform -> scalar weights).
// LDS: 64x64 f32 tile, double-buffered (32 KB), XOR-swizzled (chunk ^= row&7)
// -> 2-way per 16-lane phase on ds_read_b128 (free). Next tile's global
// loads issued before the barrier so HBM latency hides under the j-loop.
// Epilogue folds (dot + bc)*strength.
// ---------------------------------------------------------------------------
__global__ void __launch_bounds__(1024, 1)
proj_kernel(const float* __restrict__ hs, const float* __restrict__ wc,
            const float* __restrict__ we, const float* __restrict__ besum,
            const float* __restrict__ bc, const float* __restrict__ strength,
            float* __restrict__ PU) {
    __shared__ float lds[2][64 * 64];   // 32 KB
    __shared__ float part[8 * 64 * 4];  // 8 KB: wg1 partial acc
    __shared__ float vpart[64];         // wg1 partial vacc
    const int tid = threadIdx.x;
    const int lane = tid & 63;
    const int wave = __builtin_amdgcn_readfirstlane(tid >> 6);
    const int wg = wave >> 3;        // k-group 0/1
    const int w8 = wave & 7;         // output-column group
    const int R0 = blockIdx.x * 64;
    const int c0 = w8 * 4;
    const float* wbase = (c0 < 16) ? (wc + c0 * HQ) : (we + (c0 - 16) * HQ);

    // Stage geometry: tile = 64 rows x 16 float4-chunks = 1024 chunks,
    // 1024 threads -> exactly one chunk each, fully coalesced.
    const int r0s = tid >> 4;
    const int m0s = tid & 15;
    const int l0 = r0s * 64 + ((m0s ^ (r0s & 7)) << 2);
    const size_t g0 = (size_t)(R0 + r0s) * HQ + (m0s << 2);
    const int e = lane & 7;
    const int jbase = wg * 8;

    float acc0 = 0.f, acc1 = 0.f, acc2 = 0.f, acc3 = 0.f, vacc = 0.f;

    float4 sa = *(const float4*)(hs + g0);

    for (int kc = 0; kc < 16; ++kc) {
        const int k0 = kc * 64;
        float* buf = lds[kc & 1];
        *(float4*)&buf[l0] = sa;
        if (kc < 15) {  // early-issue next tile (latency hides under compute)
            sa = *(const float4*)(hs + g0 + k0 + 64);
        }
        __syncthreads();  // tile staged; double buffer covers WAR on prev buf
#pragma unroll
        for (int jj = 0; jj < 8; ++jj) {
            const int j = jbase + jj;
            float4 w0 = *(const float4*)(wbase + 0 * HQ + k0 + 4 * j);
            float4 w1 = *(const float4*)(wbase + 1 * HQ + k0 + 4 * j);
            float4 w2 = *(const float4*)(wbase + 2 * HQ + k0 + 4 * j);
            float4 w3 = *(const float4*)(wbase + 3 * HQ + k0 + 4 * j);
            // swizzled read: LDS slot (j^e) of row 'lane' holds global chunk j
            const float4 h = *(const float4*)&buf[lane * 64 + ((j ^ e) << 2)];
            acc0 = fmaf(h.x, w0.x, fmaf(h.y, w0.y, fmaf(h.z, w0.z, fmaf(h.w, w0.w, acc0))));
            acc1 = fmaf(h.x, w1.x, fmaf(h.y, w1.y, fmaf(h.z, w1.z, fmaf(h.w, w1.w, acc1))));
            acc2 = fmaf(h.x, w2.x, fmaf(h.y, w2.y, fmaf(h.z, w2.z, fmaf(h.w, w2.w, acc2))));
            acc3 = fmaf(h.x, w3.x, fmaf(h.y, w3.y, fmaf(h.z, w3.z, fmaf(h.w, w3.w, acc3))));
            if (w8 == 0) {
                float4 b4 = *(const float4*)(besum + k0 + 4 * j);
                vacc = fmaf(h.x, b4.x, fmaf(h.y, b4.y, fmaf(h.z, b4.z, fmaf(h.w, b4.w, vacc))));
            }
        }
        __syncthreads();  // all reads of buf done before it's overwritten
    }

    // combine wg1 partials into wg0, apply affine, store
    if (wg == 1) {
        *(float4*)&part[(w8 * 64 + lane) * 4] = make_float4(acc0, acc1, acc2, acc3);
        if (w8 == 0) vpart[lane] = vacc;
    }
    __syncthreads();
    if (wg == 0) {
        const float4 pr = *(const float4*)&part[(w8 * 64 + lane) * 4];
        acc0 += pr.x; acc1 += pr.y; acc2 += pr.z; acc3 += pr.w;
        const int row = R0 + lane;
        const size_t base = (size_t)row * PITCH;
        float4 o;
        if (w8 < 4) {
            const float4 st = *(const float4*)(strength + c0);
            const float4 b4 = *(const float4*)(bc + c0);
            o.x = (acc0 + b4.x) * st.x;
            o.y = (acc1 + b4.y) * st.y;
            o.z = (acc2 + b4.z) * st.z;
            o.w = (acc3 + b4.w) * st.w;
        } else {
            o = make_float4(acc0, acc1, acc2, acc3);
        }
        *(float4*)(PU + base + c0) = o;
        if (w8 == 0) PU[base + 32] = vacc + vpart[lane];
    }
}

// ---------------------------------------------------------------------------
// bias[b,s,t] = sum_r P[b,s,r]*U[b,t,r] + V[b,t]
// 128x128 tile / block, 256 threads, 8sx8t per thread. P/U/V staged in LDS
// (1 ds_read_b128 per 4 outputs instead of 2 global loads per 16 outputs).
// U tile chunk-swizzled (kq ^ (row>>3)&3): pitch-16 rows 8 apart always
// alias mod-32 banks, so padding can't help; swizzle -> 4-way max.
// Write-bound target: 268 MB nontemporal stores, 512B contiguous per phase.
// ---------------------------------------------------------------------------
__global__ void __launch_bounds__(256, 3)
bias_kernel(const float* __restrict__ PU, float* __restrict__ out) {
    __shared__ float Pl[128 * 16];
    __shared__ float Ul[128 * 16];
    __shared__ float Vl[128];
    const int b = blockIdx.z;
    const int tid = threadIdx.x;
    const int t0b = blockIdx.x * 128;
    const int s0b = blockIdx.y * 128;
    const size_t rbase = (size_t)b * SQ;
    const float4* PU4 = (const float4*)PU;

#pragma unroll
    for (int it = 0; it < 2; ++it) {
        int f = it * 256 + tid;          // 0..511
        int row = f >> 2, q = f & 3;
        float4 pv = PU4[(rbase + s0b + row) * PITCH4 + q];
        *(float4*)&Pl[row * 16 + q * 4] = pv;
        float4 uv = PU4[(rbase + t0b + row) * PITCH4 + 4 + q];
        int qs = q ^ ((row >> 3) & 3);
        *(float4*)&Ul[row * 16 + qs * 4] = uv;
    }
    if (tid < 128) Vl[tid] = PU[(rbase + t0b + tid) * PITCH + 32];
    __syncthreads();

    const int tx = tid & 15, ty = tid >> 4;
    const int ss = ty * 8, ts = tx * 8;

    float acc[8][8] = {{0.f}};
#pragma unroll
    for (int kq = 0; kq < 4; ++kq) {
        float4 p[8], u[8];
#pragma unroll
        for (int i = 0; i < 8; ++i)
            p[i] = *(const float4*)&Pl[(ss + i) * 16 + kq * 4];
#pragma unroll
        for (int j = 0; j < 8; ++j) {
            int row = ts + j;
            int qs = kq ^ ((row >> 3) & 3);
            u[j] = *(const float4*)&Ul[row * 16 + qs * 4];
        }
#pragma unroll
        for (int i = 0; i < 8; ++i)
#pragma unroll
            for (int j = 0; j < 8; ++j)
                acc[i][j] = fmaf(p[i].x, u[j].x, fmaf(p[i].y, u[j].y,
                            fmaf(p[i].z, u[j].z, fmaf(p[i].w, u[j].w, acc[i][j]))));
    }

    float v[8];
#pragma unroll
    for (int j = 0; j < 8; ++j) v[j] = Vl[ts + j];
#pragma unroll
    for (int i = 0; i < 8; ++i) {
        vfloat4 o0, o1;
        o0.x = acc[i][0] + v[0];
        o0.y = acc[i][1] + v[1];
        o0.z = acc[i][2] + v[2];
        o0.w = acc[i][3] + v[3];
        o1.x = acc[i][4] + v[4];
        o1.y = acc[i][5] + v[5];
        o1.z = acc[i][6] + v[6];
        o1.w = acc[i][7] + v[7];
        const size_t ob = (rbase + s0b + ss + i) * SQ + t0b + ts;
        __builtin_nontemporal_store(o0, (vfloat4*)(out + ob));
        __builtin_nontemporal_store(o1, (vfloat4*)(out + ob + 4));
    }
}

// ---------------------------------------------------------------------------
extern "C" void kernel_launch(void* const* d_in, const int* in_sizes, int n_in,
                              void* d_out, int out_size, void* d_ws, size_t ws_size,
                              hipStream_t stream) {
    const float* hs       = (const float*)d_in[0];  // [B,S,H]
    const float* wc       = (const float*)d_in[1];  // [R,H]
    const float* bc       = (const float*)d_in[2];  // [R]
    const float* we       = (const float*)d_in[3];  // [R,H]
    const float* be       = (const float*)d_in[4];  // [R,H]
    const float* strength = (const float*)d_in[5];  // [R]
    float* out = (float*)d_out;                     // [B,S,S]

    float* ws    = (float*)d_ws;
    float* besum = ws;              // 1024 floats
    float* PU    = besum + HQ;      // 16384*36 floats (~2.4 MB)

    besum_kernel<<<dim3(HQ / 256), dim3(256), 0, stream>>>(be, besum);
    proj_kernel<<<dim3(NROWS / 64), dim3(1024), 0, stream>>>(hs, wc, we, besum, bc, strength, PU);
    bias_kernel<<<dim3(SQ / 128, SQ / 128, BQ), dim3(256), 0, stream>>>(PU, out);
}